// Round 1
// baseline (113.007 us; speedup 1.0000x reference)
//
#include <hip/hip_runtime.h>

#define T_TOKENS 8192
#define MAX_NODES 8192
#define FEAT 256
#define NCHUNKS 128
#define CHUNK 64  // T_TOKENS / NCHUNKS

// One wave (64 lanes) per node; lane handles 4 consecutive features (float4).
// diff[start] += emb[n]; diff[end+1] -= emb[n]  (skip invalid / empty spans)
__global__ void span_scatter_kernel(const float* __restrict__ emb,
                                    const int* __restrict__ starts,
                                    const int* __restrict__ ends,
                                    const int* __restrict__ num_nodes_p,
                                    float* __restrict__ diff) {
    const int num_nodes = *num_nodes_p;
    const int node = blockIdx.x * 4 + (threadIdx.x >> 6);
    const int lane = threadIdx.x & 63;
    if (node >= num_nodes) return;
    int s = starts[node];
    const int e = ends[node];
    if (s > e || s >= T_TOKENS) return;  // empty span contributes nothing
    if (s < 0) s = 0;
    const float4 v = ((const float4*)(emb + (size_t)node * FEAT))[lane];
    float* dst = diff + (size_t)s * FEAT + lane * 4;
    atomicAdd(dst + 0, v.x);
    atomicAdd(dst + 1, v.y);
    atomicAdd(dst + 2, v.z);
    atomicAdd(dst + 3, v.w);
    if (e < T_TOKENS - 1) {
        float* dst2 = diff + (size_t)(e + 1) * FEAT + lane * 4;
        atomicAdd(dst2 + 0, -v.x);
        atomicAdd(dst2 + 1, -v.y);
        atomicAdd(dst2 + 2, -v.z);
        atomicAdd(dst2 + 3, -v.w);
    }
}

// Per-chunk column sums: block c sums its 64 token rows; thread = feature.
__global__ void chunksum_kernel(const float* __restrict__ diff,
                                float* __restrict__ colsum) {
    const int c = blockIdx.x;
    const int f = threadIdx.x;
    const float* p = diff + (size_t)c * CHUNK * FEAT + f;
    float s = 0.f;
#pragma unroll 8
    for (int t = 0; t < CHUNK; ++t) s += p[t * FEAT];
    colsum[c * FEAT + f] = s;
}

// Final: block c computes exclusive prefix over earlier chunk sums (64 KB,
// L2-resident), then inclusive-scans its 64 rows writing out coalesced.
__global__ void scan_kernel(const float* __restrict__ diff,
                            const float* __restrict__ colsum,
                            float* __restrict__ out) {
    const int c = blockIdx.x;
    const int f = threadIdx.x;
    float a0 = 0.f, a1 = 0.f, a2 = 0.f, a3 = 0.f;
    int i = 0;
    for (; i + 4 <= c; i += 4) {
        a0 += colsum[(i + 0) * FEAT + f];
        a1 += colsum[(i + 1) * FEAT + f];
        a2 += colsum[(i + 2) * FEAT + f];
        a3 += colsum[(i + 3) * FEAT + f];
    }
    for (; i < c; ++i) a0 += colsum[i * FEAT + f];
    float run = (a0 + a1) + (a2 + a3);
    const float* p = diff + (size_t)c * CHUNK * FEAT + f;
    float* o = out + (size_t)c * CHUNK * FEAT + f;
    for (int t = 0; t < CHUNK; ++t) {
        run += p[t * FEAT];
        o[t * FEAT] = run;
    }
}

extern "C" void kernel_launch(void* const* d_in, const int* in_sizes, int n_in,
                              void* d_out, int out_size, void* d_ws, size_t ws_size,
                              hipStream_t stream) {
    const float* emb      = (const float*)d_in[0];
    const int* starts     = (const int*)d_in[1];
    const int* ends       = (const int*)d_in[2];
    const int* num_nodes  = (const int*)d_in[3];
    float* out            = (float*)d_out;

    float* diff   = (float*)d_ws;                       // [T_TOKENS][FEAT]
    float* colsum = diff + (size_t)T_TOKENS * FEAT;     // [NCHUNKS][FEAT]

    hipMemsetAsync(diff, 0, (size_t)T_TOKENS * FEAT * sizeof(float), stream);

    span_scatter_kernel<<<MAX_NODES / 4, 256, 0, stream>>>(emb, starts, ends,
                                                           num_nodes, diff);
    chunksum_kernel<<<NCHUNKS, FEAT, 0, stream>>>(diff, colsum);
    scan_kernel<<<NCHUNKS, FEAT, 0, stream>>>(diff, colsum, out);
}